// Round 2
// baseline (258.305 us; speedup 1.0000x reference)
//
#include <hip/hip_runtime.h>
#include <math.h>

typedef unsigned short u16;
typedef unsigned int u32;
typedef __attribute__((ext_vector_type(8))) short short8;  // 8 bf16 (4 VGPR)
typedef __attribute__((ext_vector_type(4))) float f32x4;   // MFMA acc

#define DEVI __device__ __forceinline__

DEVI u16 f2bf(float x) {
    union { float f; u32 u; } un; un.f = x;
    u32 u = un.u;
    return (u16)((u + 0x7fffu + ((u >> 16) & 1u)) >> 16);  // RTNE
}
DEVI float bf2f(u16 v) {
    union { u32 u; float f; } un; un.u = ((u32)v) << 16;
    return un.f;
}
DEVI f32x4 mfma_bf16(short8 a, short8 b, f32x4 c) {
    return __builtin_amdgcn_mfma_f32_16x16x32_bf16(a, b, c, 0, 0, 0);
}
// async global->LDS, 16B/lane. LDS dest = wave-uniform base + lane*16.
DEVI void gload_lds16(const void* g, void* l) {
    __builtin_amdgcn_global_load_lds((const __attribute__((address_space(1))) u32*)g,
                                     (__attribute__((address_space(3))) u32*)l,
                                     16, 0, 0);
}

// ---------------- fused prep: x->bf16 convert + Wqkv^T + Wout^T ----------------
__global__ void k_prep(const float* __restrict__ x, const float* __restrict__ Wqkv,
                       const float* __restrict__ Wout, u16* __restrict__ x_bf,
                       u16* __restrict__ WqkvT, u16* __restrict__ WoutT) {
    __shared__ u16 tile[64][68];
    const int bid = blockIdx.x;
    if (bid < 4096) {
        long idx = ((long)bid * 256 + threadIdx.x) * 4;
        float4 v = *(const float4*)(x + idx);
        ushort4 o;
        o.x = f2bf(v.x); o.y = f2bf(v.y); o.z = f2bf(v.z); o.w = f2bf(v.w);
        *(ushort4*)(x_bf + idx) = o;
        return;
    }
    const float* in;
    u16* out;
    int R, C, bx, by;
    if (bid < 7168) {
        int lb = bid - 4096;
        in = Wqkv; out = WqkvT; R = 2048; C = 6144;
        bx = lb % 96; by = lb / 96;
    } else {
        int lb = bid - 7168;
        in = Wout; out = WoutT; R = 2048; C = 2048;
        bx = lb & 31; by = lb >> 5;
    }
    const int tx = threadIdx.x & 15, ty = threadIdx.x >> 4;
    const long r0 = (long)by * 64, c0 = (long)bx * 64;
#pragma unroll
    for (int p = 0; p < 4; ++p) {
        int r = ty + p * 16;
        float4 v = *(const float4*)(in + (r0 + r) * C + c0 + tx * 4);
        ushort4 o;
        o.x = f2bf(v.x); o.y = f2bf(v.y); o.z = f2bf(v.z); o.w = f2bf(v.w);
        *(ushort4*)&tile[r][tx * 4] = o;
    }
    __syncthreads();
#pragma unroll
    for (int p = 0; p < 4; ++p) {
        int rr = ty + p * 16;
        ushort4 o;
        o.x = tile[tx * 4 + 0][rr];
        o.y = tile[tx * 4 + 1][rr];
        o.z = tile[tx * 4 + 2][rr];
        o.w = tile[tx * 4 + 3][rr];
        *(ushort4*)(out + (c0 + rr) * R + r0 + tx * 4) = o;
    }
}

// ---------------- QKV GEMM: 256x256 tile, 8 waves, m201-schedule counted-vmcnt ------
// Per K-tile: 4 phases, quadrants Q00,Q10,Q11,Q01; ds_reads 12/8/4/8 (A0 re-read P4).
// Staging stagger: P1: A0(t+1)->nxt; P2/P3/P4: B0/A1/B1(t+2)->cur (each region's last
// read is the preceding phase). ONE vmcnt(6) per tile at end of P4: lands exactly the
// 4 halves of tile t+1 (issued 4-7 phases earlier), keeps 3 halves (6 loads) in flight.
__global__ __launch_bounds__(512, 2) void k_qkv256(const u16* __restrict__ A,
                                                   const u16* __restrict__ BT,
                                                   u16* __restrict__ qb, u16* __restrict__ kb,
                                                   u16* __restrict__ vtb) {
    constexpr int K = 2048, NT = K / 64;
    __shared__ __align__(16) union SM {
        struct { u16 As[2][256 * 64]; u16 Bs[2][256 * 64]; } s;  // 128 KiB, XOR-swizzled
        u16 T[128 * 264];                                        // epilogue slab (2 heads)
    } sm;
    const int tid = threadIdx.x;
    const int lane = tid & 63, wave = tid >> 6;
    const int lm = lane & 15, quad = lane >> 4;
    const int wm = wave >> 2, wn = wave & 3;  // 2M x 4N wave grid
    const int bm = blockIdx.x, bn = blockIdx.y;
    const int srow = lane >> 3;
    const int scb = (lane & 7) ^ srow;  // pre-swizzled global source chunk
    const long arow0 = (long)bm * 256;
    const long brow0 = (long)bn * 256;

    f32x4 acc[8][4] = {};   // i: 0-3 -> Ah0 rows, 4-7 -> Ah1; j: 0-1 -> Bh0 cols, 2-3 -> Bh1
    short8 a[8], b[4];

    // stage half h (128 rows x 64 cols, 16KB) of K-tile kt: 2 gload_lds16 per thread
    auto stageA = [&](int buf, int h, int kt) {
#pragma unroll
        for (int it = 0; it < 2; ++it) {
            int ch = wave * 2 + it;  // 16 chunks of 1KB (8 rows each)
            long r = h * 128 + ch * 8 + srow;
            gload_lds16(A + (arow0 + r) * K + (long)kt * 64 + scb * 8,
                        (char*)&sm.s.As[buf][h * 8192] + ch * 1024);
        }
    };
    auto stageB = [&](int buf, int h, int kt) {
#pragma unroll
        for (int it = 0; it < 2; ++it) {
            int ch = wave * 2 + it;
            long r = h * 128 + ch * 8 + srow;
            gload_lds16(BT + (brow0 + r) * K + (long)kt * 64 + scb * 8,
                        (char*)&sm.s.Bs[buf][h * 8192] + ch * 1024);
        }
    };
    auto ldA = [&](int buf, int h) {  // 8 x ds_read_b128 -> a[ii*2+ks]
#pragma unroll
        for (int ii = 0; ii < 4; ++ii) {
            int row = h * 128 + wm * 64 + ii * 16 + lm;
#pragma unroll
            for (int ks = 0; ks < 2; ++ks) {
                int pc = (ks * 4 + quad) ^ (lm & 7);
                a[ii * 2 + ks] = *(const short8*)&sm.s.As[buf][row * 64 + pc * 8];
            }
        }
    };
    auto ldB = [&](int buf, int h) {  // 4 x ds_read_b128 -> b[jj*2+ks]
#pragma unroll
        for (int jj = 0; jj < 2; ++jj) {
            int row = h * 128 + wn * 32 + jj * 16 + lm;
#pragma unroll
            for (int ks = 0; ks < 2; ++ks) {
                int pc = (ks * 4 + quad) ^ (lm & 7);
                b[jj * 2 + ks] = *(const short8*)&sm.s.Bs[buf][row * 64 + pc * 8];
            }
        }
    };
    auto mmaq = [&](int ih, int jh) {  // 16 MFMA: one C-quadrant over K=64
        __builtin_amdgcn_s_setprio(1);
#pragma unroll
        for (int ks = 0; ks < 2; ++ks)
#pragma unroll
            for (int ii = 0; ii < 4; ++ii)
#pragma unroll
                for (int jj = 0; jj < 2; ++jj)
                    acc[ih * 4 + ii][jh * 2 + jj] = mfma_bf16(
                        a[ii * 2 + ks], b[jj * 2 + ks], acc[ih * 4 + ii][jh * 2 + jj]);
        __builtin_amdgcn_s_setprio(0);
    };

#define VMW(n) asm volatile("s_waitcnt vmcnt(" #n ")" ::: "memory")
#define LGK0 asm volatile("s_waitcnt lgkmcnt(0)" ::: "memory")
#define BAR                            \
    do {                               \
        __builtin_amdgcn_s_barrier();  \
        asm volatile("" ::: "memory"); \
    } while (0)

    // prologue: tile0 (4 halves) -> vmcnt(4); B0/A1/B1 of tile1 -> vmcnt(6); barrier
    stageA(0, 0, 0); stageB(0, 0, 0); stageA(0, 1, 0); stageB(0, 1, 0);
    VMW(4);
    stageB(1, 0, 1); stageA(1, 1, 1); stageB(1, 1, 1);
    VMW(6);
    BAR;

    for (int t = 0; t < NT; ++t) {
        const int cur = t & 1, nxt = cur ^ 1;
        const int t1 = (t + 1 < NT) ? t + 1 : NT - 1;  // clamp: keeps vmcnt math uniform,
        const int t2 = (t + 2 < NT) ? t + 2 : NT - 1;  // writes land in never-read buffers
        // P1: Q00 = A0 x B0 (12 ds_reads)
        ldA(cur, 0); ldB(cur, 0);
        stageA(nxt, 0, t1);
        BAR; LGK0;
        mmaq(0, 0);
        BAR;
        // P2: Q10 = A1 x B0(regs) (8 ds_reads)
        ldA(cur, 1);
        stageB(cur, 0, t2);
        BAR; LGK0;
        mmaq(1, 0);
        BAR;
        // P3: Q11 = A1(regs) x B1 (4 ds_reads)
        ldB(cur, 1);
        stageA(cur, 1, t2);
        BAR; LGK0;
        mmaq(1, 1);
        BAR;
        // P4: Q01 = A0(re-read) x B1(regs) (8 ds_reads)
        ldA(cur, 0);
        stageB(cur, 1, t2);
        BAR; LGK0;
        mmaq(0, 1);
        VMW(6);  // lands all 4 halves of tile t+1; leaves 3 halves of t+2 in flight
        BAR;
    }
    VMW(0);  // drain clamped trailing prefetches before LDS union reuse
    BAR;

    // ---------------- epilogue: RoPE q/k or V-transpose, per 128-row half ----------------
    const int which = bn >> 3;           // 0=q, 1=k, 2=v (256-col tile within one of them)
    const int hh = tid >> 8, t8 = tid & 255;  // head-half within tile, 256-thread slice
    const int h = (bn & 7) * 2 + hh;
#pragma unroll
    for (int rh = 0; rh < 2; ++rh) {
#pragma unroll
        for (int ii = 0; ii < 4; ++ii) {
            const int i = rh * 4 + ii;
            const int row_l = wm * 64 + ii * 16 + quad * 4;
#pragma unroll
            for (int j = 0; j < 4; ++j) {
                const int col_l = (j < 2 ? wn * 32 + j * 16 : 128 + wn * 32 + (j - 2) * 16) + lm;
#pragma unroll
                for (int r = 0; r < 4; ++r)
                    sm.T[(row_l + r) * 264 + col_l] = f2bf(acc[i][j][r]);
            }
        }
        __syncthreads();
        const int tb = bm * 256 + rh * 128;
        const int b_ = tb >> 10, p0 = tb & 1023;
        if (which < 2) {
            // RoPE + store to q/k buffer [bh][pos][128]
            u16* dst = which ? kb : qb;
            const long hb = ((long)(b_ * 16 + h)) * 1024;
            const int i0 = (t8 * 4) & 63;
            const int pb = t8 >> 4;
            float inv[4];
#pragma unroll
            for (int e = 0; e < 4; ++e)
                inv[e] = exp2f(-(float)(i0 + e) * 0.20762050593045952f);  // log2(1e4)/64
#pragma unroll
            for (int c = 0; c < 8; ++c) {
                const int pos_l = c * 16 + pb;
                ushort4 cu = *(const ushort4*)&sm.T[pos_l * 264 + hh * 128 + i0];
                ushort4 pa = *(const ushort4*)&sm.T[pos_l * 264 + hh * 128 + i0 + 64];
                const float pg = (float)(p0 + pos_l);
                ushort4 o1, o2;
                const u16* cp = (const u16*)&cu;
                const u16* pp = (const u16*)&pa;
                u16* o1p = (u16*)&o1;
                u16* o2p = (u16*)&o2;
#pragma unroll
                for (int e = 0; e < 4; ++e) {
                    float th = pg * inv[e];
                    float sv = __sinf(th), cv = __cosf(th);  // |th| <= 1023
                    float x1 = bf2f(cp[e]), x2 = bf2f(pp[e]);
                    o1p[e] = f2bf(x1 * cv - x2 * sv);
                    o2p[e] = f2bf(x2 * cv + x1 * sv);
                }
                const long rowb = (hb + p0 + pos_l) * 128;
                *(ushort4*)(dst + rowb + i0) = o1;
                *(ushort4*)(dst + rowb + i0 + 64) = o2;
            }
        } else {
            // V: store transposed into vT[32][128][1024]
            const long vrow = ((long)(b_ * 16 + h)) * 128;
#pragma unroll
            for (int c = 0; c < 8; ++c) {
                const int lin = c * 2048 + t8 * 8;
                const int dk = lin >> 7;
                const int ps = lin & 127;
                ushort4 o1, o2;
                u16* o1p = (u16*)&o1;
                u16* o2p = (u16*)&o2;
#pragma unroll
                for (int e = 0; e < 4; ++e) {
                    o1p[e] = sm.T[(ps + e) * 264 + hh * 128 + dk];
                    o2p[e] = sm.T[(ps + 4 + e) * 264 + hh * 128 + dk];
                }
                u16* dstv = vtb + (vrow + dk) * 1024 + p0 + ps;
                *(ushort4*)dstv = o1;
                *(ushort4*)(dstv + 4) = o2;
            }
        }
        if (rh == 0) __syncthreads();
    }
#undef VMW
#undef LGK0
#undef BAR
}

// ---------------- m97-style bf16 GEMM (kept for out-projection, TM=64) ----------------
template <int EPI, int TM>
__global__ __launch_bounds__(256, 3) void k_gemm(const u16* __restrict__ A,
                                                 const u16* __restrict__ BT, int K,
                                                 u16* __restrict__ qb, u16* __restrict__ kb,
                                                 u16* __restrict__ vtb, float* __restrict__ out,
                                                 const float* __restrict__ bias) {
    constexpr int MI = TM / 32;
    constexpr int CA = TM / 32;
    __shared__ __align__(16) union SM {
        struct { u16 As[TM * 64]; u16 Bs[128 * 64]; } s;
        u16 T[EPI == 0 ? 128 * 132 : 8];
    } sm;
    const int tid = threadIdx.x;
    const int lane = tid & 63, wave = tid >> 6;
    const int lm = lane & 15, quad = lane >> 4;
    const int wm = wave >> 1, wn = wave & 1;
    const int bm = blockIdx.x, bn = blockIdx.y;

    f32x4 acc[MI][4] = {};

    const int srow = lane >> 3;
    const int scb = (lane & 7) ^ srow;
    const long arow0 = (long)bm * TM;
    const long brow0 = (long)bn * 128;

    for (int k0 = 0; k0 < K; k0 += 64) {
        __syncthreads();
#pragma unroll
        for (int it = 0; it < CA; ++it) {
            int ch = wave * CA + it;
            long r = ch * 8 + srow;
            gload_lds16(A + (arow0 + r) * K + k0 + scb * 8, (char*)sm.s.As + ch * 1024);
        }
#pragma unroll
        for (int it = 0; it < 4; ++it) {
            int ch = wave * 4 + it;
            long r = ch * 8 + srow;
            gload_lds16(BT + (brow0 + r) * K + k0 + scb * 8, (char*)sm.s.Bs + ch * 1024);
        }
        __syncthreads();
#pragma unroll
        for (int ko = 0; ko < 2; ++ko) {
            short8 af[MI], bf[4];
#pragma unroll
            for (int i = 0; i < MI; ++i) {
                int row = wm * (TM / 2) + i * 16 + lm;
                int pc = (ko * 4 + quad) ^ (lm & 7);
                af[i] = *(const short8*)&sm.s.As[row * 64 + pc * 8];
            }
#pragma unroll
            for (int j = 0; j < 4; ++j) {
                int row = wn * 64 + j * 16 + lm;
                int pc = (ko * 4 + quad) ^ (lm & 7);
                bf[j] = *(const short8*)&sm.s.Bs[row * 64 + pc * 8];
            }
#pragma unroll
            for (int i = 0; i < MI; ++i)
#pragma unroll
                for (int j = 0; j < 4; ++j)
                    acc[i][j] = mfma_bf16(af[i], bf[j], acc[i][j]);
        }
    }

    if constexpr (EPI == 1) {
        float bv[4];
#pragma unroll
        for (int j = 0; j < 4; ++j) bv[j] = bias[bn * 128 + wn * 64 + j * 16 + lm];
#pragma unroll
        for (int i = 0; i < MI; ++i) {
#pragma unroll
            for (int r = 0; r < 4; ++r) {
                const int row = bm * TM + wm * (TM / 2) + i * 16 + quad * 4 + r;
#pragma unroll
                for (int j = 0; j < 4; ++j) {
                    const int col = bn * 128 + wn * 64 + j * 16 + lm;
                    out[(long)row * 2048 + col] = acc[i][j][r] + bv[j];
                }
            }
        }
    }
}

// ---------------- flash attention (causal), S^T = K*Q^T, swizzled LDS ----------------
__global__ __launch_bounds__(256, 3) void k_flash(const u16* __restrict__ Q,
                                                  const u16* __restrict__ Kb,
                                                  const u16* __restrict__ VT,
                                                  u16* __restrict__ R) {
    __shared__ u16 Ks[64 * 128];  // [key 64][d 128], swizzled mask 15
    __shared__ u16 Vs[128 * 64];  // [d 128][key 64], swizzled mask 7
    __shared__ u16 Ps[64 * 72];   // [q 64][key 64 + 8 pad]
    const int tid = threadIdx.x;
    const int lane = tid & 63, wave = tid >> 6;
    const int lm = lane & 15, quad = lane >> 4;
    const int id = blockIdx.x;
    const int g = id >> 8, rem = id & 255;
    const int bh = rem >> 3, s = rem & 7;
    const int qt = g ? (15 - s) : s;
    const long qkbase = (long)bh * 1024 * 128;
    const long vtbase = (long)bh * 128 * 1024;
    const int q0 = qt * 64;

    short8 qf[4];
    {
        const u16* qrow = Q + qkbase + (long)(q0 + wave * 16 + lm) * 128 + quad * 8;
#pragma unroll
        for (int kc = 0; kc < 4; ++kc) qf[kc] = *(const short8*)(qrow + kc * 32);
    }

    f32x4 o_acc[8] = {};
    float m_i = -INFINITY, l_i = 0.f;
    const float cl2e = 0.08838834764831845f * 1.4426950408889634f;  // 1/sqrt(128)*log2(e)

    const int kr = lane >> 4;
    const int vr = lane >> 3;
    const int vcb = (lane & 7) ^ vr;

    for (int kt = 0; kt <= qt; ++kt) {
        __syncthreads();
        {
#pragma unroll
            for (int it = 0; it < 4; ++it) {
                int ch = wave * 4 + it;
                int krow = ch * 4 + kr;
                int kchunk = (lane & 15) ^ (krow & 15);
                gload_lds16(Kb + qkbase + (long)(kt * 64 + krow) * 128 + kchunk * 8,
                            (char*)Ks + ch * 1024);
                int vrow = ch * 8 + vr;
                gload_lds16(VT + vtbase + (long)vrow * 1024 + kt * 64 + vcb * 8,
                            (char*)Vs + ch * 1024);
            }
        }
        __syncthreads();

        f32x4 s_acc[4] = {};
#pragma unroll
        for (int kc = 0; kc < 4; ++kc) {
#pragma unroll
            for (int mi = 0; mi < 4; ++mi) {
                int row = mi * 16 + lm;
                int pc = (kc * 4 + quad) ^ lm;
                short8 ak = *(const short8*)&Ks[row * 128 + pc * 8];
                s_acc[mi] = mfma_bf16(ak, qf[kc], s_acc[mi]);
            }
        }
        const int qg = q0 + wave * 16 + lm;
        float t[4][4];
        float cmax = -INFINITY;
#pragma unroll
        for (int mi = 0; mi < 4; ++mi)
#pragma unroll
            for (int r = 0; r < 4; ++r) {
                int kg = kt * 64 + mi * 16 + quad * 4 + r;
                float val = (kg <= qg) ? s_acc[mi][r] * cl2e : -INFINITY;
                t[mi][r] = val;
                cmax = fmaxf(cmax, val);
            }
        cmax = fmaxf(cmax, __shfl_xor(cmax, 16));
        cmax = fmaxf(cmax, __shfl_xor(cmax, 32));
        float m_new = fmaxf(m_i, cmax);
        float alpha = exp2f(m_i - m_new);
        float csum = 0.f;
#pragma unroll
        for (int mi = 0; mi < 4; ++mi)
#pragma unroll
            for (int r = 0; r < 4; ++r) {
                float p = exp2f(t[mi][r] - m_new);
                t[mi][r] = p;
                csum += p;
            }
        csum += __shfl_xor(csum, 16);
        csum += __shfl_xor(csum, 32);
        l_i = l_i * alpha + csum;
        m_i = m_new;
#pragma unroll
        for (int mi = 0; mi < 4; ++mi) {
            ushort4 pk;
            pk.x = f2bf(t[mi][0]); pk.y = f2bf(t[mi][1]);
            pk.z = f2bf(t[mi][2]); pk.w = f2bf(t[mi][3]);
            *(ushort4*)&Ps[(wave * 16 + lm) * 72 + mi * 16 + quad * 4] = pk;
        }
        float aq[4];
#pragma unroll
        for (int r = 0; r < 4; ++r) aq[r] = __shfl(alpha, quad * 4 + r, 64);
#pragma unroll
        for (int nt = 0; nt < 8; ++nt)
#pragma unroll
            for (int r = 0; r < 4; ++r) o_acc[nt][r] *= aq[r];
#pragma unroll
        for (int kc = 0; kc < 2; ++kc) {
            short8 ap = *(const short8*)&Ps[(wave * 16 + lm) * 72 + kc * 32 + quad * 8];
#pragma unroll
            for (int nt = 0; nt < 8; ++nt) {
                int row = nt * 16 + lm;
                int pc = (kc * 4 + quad) ^ (lm & 7);
                short8 bv = *(const short8*)&Vs[row * 64 + pc * 8];
                o_acc[nt] = mfma_bf16(ap, bv, o_acc[nt]);
            }
        }
    }
    float lq[4];
#pragma unroll
    for (int r = 0; r < 4; ++r) lq[r] = __shfl(l_i, quad * 4 + r, 64);
    const int b = bh >> 4, h = bh & 15;
#pragma unroll
    for (int nt = 0; nt < 8; ++nt)
#pragma unroll
        for (int r = 0; r < 4; ++r) {
            const int pos = q0 + wave * 16 + quad * 4 + r;
            const int col = h * 128 + nt * 16 + lm;
            R[((long)b * 1024 + pos) * 2048 + col] = f2bf(o_acc[nt][r] / lq[r]);
        }
}

extern "C" void kernel_launch(void* const* d_in, const int* in_sizes, int n_in,
                              void* d_out, int out_size, void* d_ws, size_t ws_size,
                              hipStream_t stream) {
    const float* x    = (const float*)d_in[0];
    const float* Wqkv = (const float*)d_in[2];
    const float* Wout = (const float*)d_in[3];
    const float* bout = (const float*)d_in[4];
    float* out = (float*)d_out;

    char* ws = (char*)d_ws;
    u16* x_bf  = (u16*)(ws);                 // 8MB; dead after qkv GEMM
    u16* rbuf  = x_bf;                       // reuse: written by flash
    u16* WqkvT = (u16*)(ws + (8L << 20));    // 24MB
    u16* WoutT = (u16*)(ws + (32L << 20));   // 8MB
    u16* qbuf  = (u16*)(ws + (40L << 20));   // 8MB (roped)
    u16* kbuf  = (u16*)(ws + (48L << 20));   // 8MB (roped)
    u16* vtbuf = (u16*)(ws + (56L << 20));   // 8MB, vT[32][128][1024]

    k_prep<<<8192, 256, 0, stream>>>(x, Wqkv, Wout, x_bf, WqkvT, WoutT);
    k_qkv256<<<dim3(8, 24), 512, 0, stream>>>(x_bf, WqkvT, qbuf, kbuf, vtbuf);
    k_flash<<<512, 256, 0, stream>>>(qbuf, kbuf, vtbuf, rbuf);
    k_gemm<1, 64><<<dim3(32, 16), 256, 0, stream>>>(rbuf, WoutT, 2048, nullptr, nullptr,
                                                    nullptr, out, bout);
}

// Round 3
// 240.206 us; speedup vs baseline: 1.0753x; 1.0753x over previous
//
#include <hip/hip_runtime.h>
#include <math.h>

typedef unsigned short u16;
typedef unsigned int u32;
typedef __attribute__((ext_vector_type(8))) short short8;  // 8 bf16 (4 VGPR)
typedef __attribute__((ext_vector_type(4))) float f32x4;   // MFMA acc

#define DEVI __device__ __forceinline__

DEVI u16 f2bf(float x) {
    union { float f; u32 u; } un; un.f = x;
    u32 u = un.u;
    return (u16)((u + 0x7fffu + ((u >> 16) & 1u)) >> 16);  // RTNE
}
DEVI float bf2f(u16 v) {
    union { u32 u; float f; } un; un.u = ((u32)v) << 16;
    return un.f;
}
DEVI f32x4 mfma_bf16(short8 a, short8 b, f32x4 c) {
    return __builtin_amdgcn_mfma_f32_16x16x32_bf16(a, b, c, 0, 0, 0);
}
// async global->LDS, 16B/lane. LDS dest = wave-uniform base + lane*16.
DEVI void gload_lds16(const void* g, void* l) {
    __builtin_amdgcn_global_load_lds((const __attribute__((address_space(1))) u32*)g,
                                     (__attribute__((address_space(3))) u32*)l,
                                     16, 0, 0);
}

// ---------------- fused prep: x->bf16 convert + Wqkv^T + Wout^T ----------------
__global__ void k_prep(const float* __restrict__ x, const float* __restrict__ Wqkv,
                       const float* __restrict__ Wout, u16* __restrict__ x_bf,
                       u16* __restrict__ WqkvT, u16* __restrict__ WoutT) {
    __shared__ u16 tile[64][68];
    const int bid = blockIdx.x;
    if (bid < 4096) {
        long idx = ((long)bid * 256 + threadIdx.x) * 4;
        float4 v = *(const float4*)(x + idx);
        ushort4 o;
        o.x = f2bf(v.x); o.y = f2bf(v.y); o.z = f2bf(v.z); o.w = f2bf(v.w);
        *(ushort4*)(x_bf + idx) = o;
        return;
    }
    const float* in;
    u16* out;
    int R, C, bx, by;
    if (bid < 7168) {
        int lb = bid - 4096;
        in = Wqkv; out = WqkvT; R = 2048; C = 6144;
        bx = lb % 96; by = lb / 96;
    } else {
        int lb = bid - 7168;
        in = Wout; out = WoutT; R = 2048; C = 2048;
        bx = lb & 31; by = lb >> 5;
    }
    const int tx = threadIdx.x & 15, ty = threadIdx.x >> 4;
    const long r0 = (long)by * 64, c0 = (long)bx * 64;
#pragma unroll
    for (int p = 0; p < 4; ++p) {
        int r = ty + p * 16;
        float4 v = *(const float4*)(in + (r0 + r) * C + c0 + tx * 4);
        ushort4 o;
        o.x = f2bf(v.x); o.y = f2bf(v.y); o.z = f2bf(v.z); o.w = f2bf(v.w);
        *(ushort4*)&tile[r][tx * 4] = o;
    }
    __syncthreads();
#pragma unroll
    for (int p = 0; p < 4; ++p) {
        int rr = ty + p * 16;
        ushort4 o;
        o.x = tile[tx * 4 + 0][rr];
        o.y = tile[tx * 4 + 1][rr];
        o.z = tile[tx * 4 + 2][rr];
        o.w = tile[tx * 4 + 3][rr];
        *(ushort4*)(out + (c0 + rr) * R + r0 + tx * 4) = o;
    }
}

// ---------------- m97-style bf16 GEMM, XOR-swizzled LDS, templated tile-M ----------------
// C[bm*TM..+TM, bn*128..+128] = A[M,K] * BT[N,K]^T.
// EPI 0 (TM=128): QKV epilogue — RoPE q/k, v transposed into vT[32][128][1024].
// EPI 1 (TM=64):  +bias, fp32 store (smaller tile -> 512 blocks -> 2-3/CU).
template <int EPI, int TM>
__global__ __launch_bounds__(256, 3) void k_gemm(const u16* __restrict__ A,
                                                 const u16* __restrict__ BT, int K,
                                                 u16* __restrict__ qb, u16* __restrict__ kb,
                                                 u16* __restrict__ vtb, float* __restrict__ out,
                                                 const float* __restrict__ bias) {
    constexpr int MI = TM / 32;       // A-frags per wave (4 for TM=128, 2 for TM=64)
    constexpr int CA = TM / 32;       // A staging chunks per wave (nchA = TM/8, /4 waves)
    __shared__ __align__(16) union SM {
        struct { u16 As[TM * 64]; u16 Bs[128 * 64]; } s;   // swizzled staging
        u16 T[EPI == 0 ? 128 * 132 : 8];                   // epilogue tile (pad 132)
    } sm;
    const int tid = threadIdx.x;
    const int lane = tid & 63, wave = tid >> 6;
    const int lm = lane & 15, quad = lane >> 4;
    const int wm = wave >> 1, wn = wave & 1;
    const int bm = blockIdx.x, bn = blockIdx.y;

    f32x4 acc[MI][4] = {};

    const int srow = lane >> 3;
    const int scb = (lane & 7) ^ srow;
    const long arow0 = (long)bm * TM;
    const long brow0 = (long)bn * 128;

    for (int k0 = 0; k0 < K; k0 += 64) {
        __syncthreads();
#pragma unroll
        for (int it = 0; it < CA; ++it) {
            int ch = wave * CA + it;
            long r = ch * 8 + srow;
            gload_lds16(A + (arow0 + r) * K + k0 + scb * 8, (char*)sm.s.As + ch * 1024);
        }
#pragma unroll
        for (int it = 0; it < 4; ++it) {
            int ch = wave * 4 + it;
            long r = ch * 8 + srow;
            gload_lds16(BT + (brow0 + r) * K + k0 + scb * 8, (char*)sm.s.Bs + ch * 1024);
        }
        __syncthreads();
#pragma unroll
        for (int ko = 0; ko < 2; ++ko) {
            short8 af[MI], bf[4];
#pragma unroll
            for (int i = 0; i < MI; ++i) {
                int row = wm * (TM / 2) + i * 16 + lm;
                int pc = (ko * 4 + quad) ^ (lm & 7);
                af[i] = *(const short8*)&sm.s.As[row * 64 + pc * 8];
            }
#pragma unroll
            for (int j = 0; j < 4; ++j) {
                int row = wn * 64 + j * 16 + lm;
                int pc = (ko * 4 + quad) ^ (lm & 7);
                bf[j] = *(const short8*)&sm.s.Bs[row * 64 + pc * 8];
            }
#pragma unroll
            for (int i = 0; i < MI; ++i)
#pragma unroll
                for (int j = 0; j < 4; ++j)
                    acc[i][j] = mfma_bf16(af[i], bf[j], acc[i][j]);
        }
    }

    if constexpr (EPI == 0) {
        __syncthreads();  // all waves done reading As/Bs
#pragma unroll
        for (int i = 0; i < MI; ++i)
#pragma unroll
            for (int j = 0; j < 4; ++j) {
                const int col = wn * 64 + j * 16 + lm;
#pragma unroll
                for (int r = 0; r < 4; ++r) {
                    const int row = wm * 64 + i * 16 + quad * 4 + r;
                    sm.T[row * 132 + col] = f2bf(acc[i][j][r]);
                }
            }
        __syncthreads();
        const int which = bn >> 4, h = bn & 15, b = bm >> 3;
        const int p0 = (bm & 7) * 128;
        if (which < 2) {
            // RoPE + store to q/k buffer [bh][pos][128]
            u16* dst = which ? kb : qb;
            const long hb = ((long)(b * 16 + h)) * 1024;
            const int i0 = (tid * 4) & 63;   // c-invariant
            const int pb = tid >> 4;         // pos_l = c*16 + pb
            float inv[4];
#pragma unroll
            for (int e = 0; e < 4; ++e)
                inv[e] = exp2f(-(float)(i0 + e) * 0.20762050593045952f);  // log2(1e4)/64
#pragma unroll
            for (int c = 0; c < 8; ++c) {
                const int pos_l = c * 16 + pb;
                ushort4 cur = *(const ushort4*)&sm.T[pos_l * 132 + i0];
                ushort4 par = *(const ushort4*)&sm.T[pos_l * 132 + i0 + 64];
                const float pg = (float)(p0 + pos_l);
                ushort4 o1, o2;
                const u16* cp = (const u16*)&cur;
                const u16* pp = (const u16*)&par;
                u16* o1p = (u16*)&o1;
                u16* o2p = (u16*)&o2;
#pragma unroll
                for (int e = 0; e < 4; ++e) {
                    float th = pg * inv[e];
                    float sv = __sinf(th), cv = __cosf(th);  // v_sin/v_cos, |th|<=1023
                    float x1 = bf2f(cp[e]), x2 = bf2f(pp[e]);
                    o1p[e] = f2bf(x1 * cv - x2 * sv);
                    o2p[e] = f2bf(x2 * cv + x1 * sv);
                }
                const long rowb = (hb + p0 + pos_l) * 128;
                *(ushort4*)(dst + rowb + i0) = o1;
                *(ushort4*)(dst + rowb + i0 + 64) = o2;
            }
        } else {
            // V: store transposed into vT[32][128][1024]
            const long vrow = ((long)(b * 16 + h)) * 128;
#pragma unroll
            for (int c = 0; c < 8; ++c) {
                const int lin = c * 2048 + tid * 8;
                const int dk = lin >> 7;
                const int ps = lin & 127;
                ushort4 o1, o2;
                u16* o1p = (u16*)&o1;
                u16* o2p = (u16*)&o2;
#pragma unroll
                for (int e = 0; e < 4; ++e) {
                    o1p[e] = sm.T[(ps + e) * 132 + dk];
                    o2p[e] = sm.T[(ps + 4 + e) * 132 + dk];
                }
                u16* dst = vtb + (vrow + dk) * 1024 + p0 + ps;
                *(ushort4*)dst = o1;
                *(ushort4*)(dst + 4) = o2;
            }
        }
    } else {
        float bv[4];
#pragma unroll
        for (int j = 0; j < 4; ++j) bv[j] = bias[bn * 128 + wn * 64 + j * 16 + lm];
#pragma unroll
        for (int i = 0; i < MI; ++i) {
#pragma unroll
            for (int r = 0; r < 4; ++r) {
                const int row = bm * TM + wm * (TM / 2) + i * 16 + quad * 4 + r;
#pragma unroll
                for (int j = 0; j < 4; ++j) {
                    const int col = bn * 128 + wn * 64 + j * 16 + lm;
                    out[(long)row * 2048 + col] = acc[i][j][r] + bv[j];
                }
            }
        }
    }
}

// ---------------- flash attention (causal), S^T = K*Q^T, 2-phase dbuf prefetch ---------
// K/V for tile kt+1 issued (gload_lds, no wait) BEFORE compute of tile kt; the single
// end-of-iter __syncthreads (implicit vmcnt(0)+lgkmcnt(0)) lands the prefetch under
// ~600+ cycles of QK^T+softmax+PV. One barrier per iter. LDS 73KB -> 2 blocks/CU (=grid).
__global__ __launch_bounds__(256, 2) void k_flash(const u16* __restrict__ Q,
                                                  const u16* __restrict__ Kb,
                                                  const u16* __restrict__ VT,
                                                  u16* __restrict__ R) {
    __shared__ u16 Ks[2][64 * 128];  // [key 64][d 128], swizzled mask 15
    __shared__ u16 Vs[2][128 * 64];  // [d 128][key 64], swizzled mask 7
    __shared__ u16 Ps[64 * 72];      // [q 64][key 64 + 8 pad]
    const int tid = threadIdx.x;
    const int lane = tid & 63, wave = tid >> 6;
    const int lm = lane & 15, quad = lane >> 4;
    const int id = blockIdx.x;
    const int g = id >> 8, rem = id & 255;
    const int bh = rem >> 3, s = rem & 7;
    const int qt = g ? (15 - s) : s;
    const long qkbase = (long)bh * 1024 * 128;
    const long vtbase = (long)bh * 128 * 1024;
    const int q0 = qt * 64;

    short8 qf[4];
    {
        const u16* qrow = Q + qkbase + (long)(q0 + wave * 16 + lm) * 128 + quad * 8;
#pragma unroll
        for (int kc = 0; kc < 4; ++kc) qf[kc] = *(const short8*)(qrow + kc * 32);
    }

    f32x4 o_acc[8] = {};
    float m_i = -INFINITY, l_i = 0.f;
    const float cl2e = 0.08838834764831845f * 1.4426950408889634f;  // 1/sqrt(128)*log2(e)

    const int kr = lane >> 4;
    const int vr = lane >> 3;
    const int vcb = (lane & 7) ^ vr;

    auto stage = [&](int buf, int kt) {
#pragma unroll
        for (int it = 0; it < 4; ++it) {
            int ch = wave * 4 + it;
            int krow = ch * 4 + kr;
            int kchunk = (lane & 15) ^ (krow & 15);
            gload_lds16(Kb + qkbase + (long)(kt * 64 + krow) * 128 + kchunk * 8,
                        (char*)Ks[buf] + ch * 1024);
            int vrow = ch * 8 + vr;
            gload_lds16(VT + vtbase + (long)vrow * 1024 + kt * 64 + vcb * 8,
                        (char*)Vs[buf] + ch * 1024);
        }
    };

    stage(0, 0);
    __syncthreads();  // implicit vmcnt(0): tile 0 ready
    int cur = 0;

    for (int kt = 0; kt <= qt; ++kt) {
        if (kt < qt) stage(cur ^ 1, kt + 1);  // issue prefetch, no wait
        asm volatile("" ::: "memory");        // keep issue before compute

        f32x4 s_acc[4] = {};
#pragma unroll
        for (int kc = 0; kc < 4; ++kc) {
#pragma unroll
            for (int mi = 0; mi < 4; ++mi) {
                int row = mi * 16 + lm;
                int pc = (kc * 4 + quad) ^ lm;
                short8 ak = *(const short8*)&Ks[cur][row * 128 + pc * 8];
                s_acc[mi] = mfma_bf16(ak, qf[kc], s_acc[mi]);
            }
        }
        const int qg = q0 + wave * 16 + lm;
        float t[4][4];
        float cmax = -INFINITY;
#pragma unroll
        for (int mi = 0; mi < 4; ++mi)
#pragma unroll
            for (int r = 0; r < 4; ++r) {
                int kg = kt * 64 + mi * 16 + quad * 4 + r;
                float val = (kg <= qg) ? s_acc[mi][r] * cl2e : -INFINITY;
                t[mi][r] = val;
                cmax = fmaxf(cmax, val);
            }
        cmax = fmaxf(cmax, __shfl_xor(cmax, 16));
        cmax = fmaxf(cmax, __shfl_xor(cmax, 32));
        float m_new = fmaxf(m_i, cmax);
        float alpha = exp2f(m_i - m_new);
        float csum = 0.f;
#pragma unroll
        for (int mi = 0; mi < 4; ++mi)
#pragma unroll
            for (int r = 0; r < 4; ++r) {
                float p = exp2f(t[mi][r] - m_new);
                t[mi][r] = p;
                csum += p;
            }
        csum += __shfl_xor(csum, 16);
        csum += __shfl_xor(csum, 32);
        l_i = l_i * alpha + csum;
        m_i = m_new;
#pragma unroll
        for (int mi = 0; mi < 4; ++mi) {
            ushort4 pk;
            pk.x = f2bf(t[mi][0]); pk.y = f2bf(t[mi][1]);
            pk.z = f2bf(t[mi][2]); pk.w = f2bf(t[mi][3]);
            *(ushort4*)&Ps[(wave * 16 + lm) * 72 + mi * 16 + quad * 4] = pk;
        }
        float aq[4];
#pragma unroll
        for (int r = 0; r < 4; ++r) aq[r] = __shfl(alpha, quad * 4 + r, 64);
#pragma unroll
        for (int nt = 0; nt < 8; ++nt)
#pragma unroll
            for (int r = 0; r < 4; ++r) o_acc[nt][r] *= aq[r];
#pragma unroll
        for (int kc = 0; kc < 2; ++kc) {
            short8 ap = *(const short8*)&Ps[(wave * 16 + lm) * 72 + kc * 32 + quad * 8];
#pragma unroll
            for (int nt = 0; nt < 8; ++nt) {
                int row = nt * 16 + lm;
                int pc = (kc * 4 + quad) ^ (lm & 7);
                short8 bv = *(const short8*)&Vs[cur][row * 64 + pc * 8];
                o_acc[nt] = mfma_bf16(ap, bv, o_acc[nt]);
            }
        }
        __syncthreads();  // implicit vmcnt(0): prefetch landed; Ps WAR fence
        cur ^= 1;
    }
    float lq[4];
#pragma unroll
    for (int r = 0; r < 4; ++r) lq[r] = __shfl(l_i, quad * 4 + r, 64);
    const int b = bh >> 4, h = bh & 15;
#pragma unroll
    for (int nt = 0; nt < 8; ++nt)
#pragma unroll
        for (int r = 0; r < 4; ++r) {
            const int pos = q0 + wave * 16 + quad * 4 + r;
            const int col = h * 128 + nt * 16 + lm;
            R[((long)b * 1024 + pos) * 2048 + col] = f2bf(o_acc[nt][r] / lq[r]);
        }
}

extern "C" void kernel_launch(void* const* d_in, const int* in_sizes, int n_in,
                              void* d_out, int out_size, void* d_ws, size_t ws_size,
                              hipStream_t stream) {
    const float* x    = (const float*)d_in[0];
    const float* Wqkv = (const float*)d_in[2];
    const float* Wout = (const float*)d_in[3];
    const float* bout = (const float*)d_in[4];
    float* out = (float*)d_out;

    char* ws = (char*)d_ws;
    u16* x_bf  = (u16*)(ws);                 // 8MB; dead after qkv GEMM
    u16* rbuf  = x_bf;                       // reuse: written by flash
    u16* WqkvT = (u16*)(ws + (8L << 20));    // 24MB
    u16* WoutT = (u16*)(ws + (32L << 20));   // 8MB
    u16* qbuf  = (u16*)(ws + (40L << 20));   // 8MB (roped)
    u16* kbuf  = (u16*)(ws + (48L << 20));   // 8MB (roped)
    u16* vtbuf = (u16*)(ws + (56L << 20));   // 8MB, vT[32][128][1024]

    k_prep<<<8192, 256, 0, stream>>>(x, Wqkv, Wout, x_bf, WqkvT, WoutT);
    k_gemm<0, 128><<<dim3(16, 48), 256, 0, stream>>>(x_bf, WqkvT, 2048, qbuf, kbuf, vtbuf,
                                                     nullptr, nullptr);
    k_flash<<<512, 256, 0, stream>>>(qbuf, kbuf, vtbuf, rbuf);
    k_gemm<1, 64><<<dim3(32, 16), 256, 0, stream>>>(rbuf, WoutT, 2048, nullptr, nullptr,
                                                    nullptr, out, bout);
}

// Round 4
// 236.502 us; speedup vs baseline: 1.0922x; 1.0157x over previous
//
#include <hip/hip_runtime.h>
#include <math.h>

typedef unsigned short u16;
typedef unsigned int u32;
typedef __attribute__((ext_vector_type(8))) short short8;  // 8 bf16 (4 VGPR)
typedef __attribute__((ext_vector_type(4))) float f32x4;   // MFMA acc

#define DEVI __device__ __forceinline__

DEVI u16 f2bf(float x) {
    union { float f; u32 u; } un; un.f = x;
    u32 u = un.u;
    return (u16)((u + 0x7fffu + ((u >> 16) & 1u)) >> 16);  // RTNE
}
DEVI float bf2f(u16 v) {
    union { u32 u; float f; } un; un.u = ((u32)v) << 16;
    return un.f;
}
DEVI f32x4 mfma_bf16(short8 a, short8 b, f32x4 c) {
    return __builtin_amdgcn_mfma_f32_16x16x32_bf16(a, b, c, 0, 0, 0);
}
// async global->LDS, 16B/lane. LDS dest = wave-uniform base + lane*16.
DEVI void gload_lds16(const void* g, void* l) {
    __builtin_amdgcn_global_load_lds((const __attribute__((address_space(1))) u32*)g,
                                     (__attribute__((address_space(3))) u32*)l,
                                     16, 0, 0);
}

// ---------------- fused prep: x->bf16 convert + Wqkv^T + Wout^T ----------------
__global__ void k_prep(const float* __restrict__ x, const float* __restrict__ Wqkv,
                       const float* __restrict__ Wout, u16* __restrict__ x_bf,
                       u16* __restrict__ WqkvT, u16* __restrict__ WoutT) {
    __shared__ u16 tile[64][68];
    const int bid = blockIdx.x;
    if (bid < 4096) {
        long idx = ((long)bid * 256 + threadIdx.x) * 4;
        float4 v = *(const float4*)(x + idx);
        ushort4 o;
        o.x = f2bf(v.x); o.y = f2bf(v.y); o.z = f2bf(v.z); o.w = f2bf(v.w);
        *(ushort4*)(x_bf + idx) = o;
        return;
    }
    const float* in;
    u16* out;
    int R, C, bx, by;
    if (bid < 7168) {
        int lb = bid - 4096;
        in = Wqkv; out = WqkvT; R = 2048; C = 6144;
        bx = lb % 96; by = lb / 96;
    } else {
        int lb = bid - 7168;
        in = Wout; out = WoutT; R = 2048; C = 2048;
        bx = lb & 31; by = lb >> 5;
    }
    const int tx = threadIdx.x & 15, ty = threadIdx.x >> 4;
    const long r0 = (long)by * 64, c0 = (long)bx * 64;
#pragma unroll
    for (int p = 0; p < 4; ++p) {
        int r = ty + p * 16;
        float4 v = *(const float4*)(in + (r0 + r) * C + c0 + tx * 4);
        ushort4 o;
        o.x = f2bf(v.x); o.y = f2bf(v.y); o.z = f2bf(v.z); o.w = f2bf(v.w);
        *(ushort4*)&tile[r][tx * 4] = o;
    }
    __syncthreads();
#pragma unroll
    for (int p = 0; p < 4; ++p) {
        int rr = ty + p * 16;
        ushort4 o;
        o.x = tile[tx * 4 + 0][rr];
        o.y = tile[tx * 4 + 1][rr];
        o.z = tile[tx * 4 + 2][rr];
        o.w = tile[tx * 4 + 3][rr];
        *(ushort4*)(out + (c0 + rr) * R + r0 + tx * 4) = o;
    }
}

// ---------------- m97-style bf16 GEMM, XOR-swizzled LDS, templated tile-M ----------------
// C[bm*TM..+TM, bn*128..+128] = A[M,K] * BT[N,K]^T.
// T1 XCD swizzle: contiguous work chunk per XCD so B-panels become L2-resident
// (FETCH was 3.2x unique inputs = L2 thrash). Grids are multiples of 8 -> bijective.
// EPI 0 (TM=128): QKV epilogue — RoPE q/k, v transposed into vT[32][128][1024].
// EPI 1 (TM=64):  +bias, fp32 store (smaller tile -> 512 blocks -> 2-3/CU).
template <int EPI, int TM>
__global__ __launch_bounds__(256, 3) void k_gemm(const u16* __restrict__ A,
                                                 const u16* __restrict__ BT, int K,
                                                 u16* __restrict__ qb, u16* __restrict__ kb,
                                                 u16* __restrict__ vtb, float* __restrict__ out,
                                                 const float* __restrict__ bias) {
    constexpr int MI = TM / 32;       // A-frags per wave (4 for TM=128, 2 for TM=64)
    constexpr int CA = TM / 32;       // A staging chunks per wave (nchA = TM/8, /4 waves)
    __shared__ __align__(16) union SM {
        struct { u16 As[TM * 64]; u16 Bs[128 * 64]; } s;   // swizzled staging
        u16 T[EPI == 0 ? 128 * 132 : 8];                   // epilogue tile (pad 132)
    } sm;
    const int tid = threadIdx.x;
    const int lane = tid & 63, wave = tid >> 6;
    const int lm = lane & 15, quad = lane >> 4;
    const int wm = wave >> 1, wn = wave & 1;
    // T1: XCD-aware block swizzle (dispatch id%8 ~ XCD; give each XCD a contiguous chunk)
    const int nwg = gridDim.x * gridDim.y;
    const int lin = blockIdx.y * gridDim.x + blockIdx.x;
    const int work = (lin & 7) * (nwg >> 3) + (lin >> 3);
    const int bm = work % gridDim.x, bn = work / gridDim.x;

    f32x4 acc[MI][4] = {};

    const int srow = lane >> 3;
    const int scb = (lane & 7) ^ srow;
    const long arow0 = (long)bm * TM;
    const long brow0 = (long)bn * 128;

    for (int k0 = 0; k0 < K; k0 += 64) {
        __syncthreads();
#pragma unroll
        for (int it = 0; it < CA; ++it) {
            int ch = wave * CA + it;
            long r = ch * 8 + srow;
            gload_lds16(A + (arow0 + r) * K + k0 + scb * 8, (char*)sm.s.As + ch * 1024);
        }
#pragma unroll
        for (int it = 0; it < 4; ++it) {
            int ch = wave * 4 + it;
            long r = ch * 8 + srow;
            gload_lds16(BT + (brow0 + r) * K + k0 + scb * 8, (char*)sm.s.Bs + ch * 1024);
        }
        __syncthreads();
#pragma unroll
        for (int ko = 0; ko < 2; ++ko) {
            short8 af[MI], bf[4];
#pragma unroll
            for (int i = 0; i < MI; ++i) {
                int row = wm * (TM / 2) + i * 16 + lm;
                int pc = (ko * 4 + quad) ^ (lm & 7);
                af[i] = *(const short8*)&sm.s.As[row * 64 + pc * 8];
            }
#pragma unroll
            for (int j = 0; j < 4; ++j) {
                int row = wn * 64 + j * 16 + lm;
                int pc = (ko * 4 + quad) ^ (lm & 7);
                bf[j] = *(const short8*)&sm.s.Bs[row * 64 + pc * 8];
            }
#pragma unroll
            for (int i = 0; i < MI; ++i)
#pragma unroll
                for (int j = 0; j < 4; ++j)
                    acc[i][j] = mfma_bf16(af[i], bf[j], acc[i][j]);
        }
    }

    if constexpr (EPI == 0) {
        __syncthreads();  // all waves done reading As/Bs
#pragma unroll
        for (int i = 0; i < MI; ++i)
#pragma unroll
            for (int j = 0; j < 4; ++j) {
                const int col = wn * 64 + j * 16 + lm;
#pragma unroll
                for (int r = 0; r < 4; ++r) {
                    const int row = wm * 64 + i * 16 + quad * 4 + r;
                    sm.T[row * 132 + col] = f2bf(acc[i][j][r]);
                }
            }
        __syncthreads();
        const int which = bn >> 4, h = bn & 15, b = bm >> 3;
        const int p0 = (bm & 7) * 128;
        if (which < 2) {
            // RoPE + store to q/k buffer [bh][pos][128]
            u16* dst = which ? kb : qb;
            const long hb = ((long)(b * 16 + h)) * 1024;
            const int i0 = (tid * 4) & 63;   // c-invariant
            const int pb = tid >> 4;         // pos_l = c*16 + pb
            float inv[4];
#pragma unroll
            for (int e = 0; e < 4; ++e)
                inv[e] = exp2f(-(float)(i0 + e) * 0.20762050593045952f);  // log2(1e4)/64
#pragma unroll
            for (int c = 0; c < 8; ++c) {
                const int pos_l = c * 16 + pb;
                ushort4 cur = *(const ushort4*)&sm.T[pos_l * 132 + i0];
                ushort4 par = *(const ushort4*)&sm.T[pos_l * 132 + i0 + 64];
                const float pg = (float)(p0 + pos_l);
                ushort4 o1, o2;
                const u16* cp = (const u16*)&cur;
                const u16* pp = (const u16*)&par;
                u16* o1p = (u16*)&o1;
                u16* o2p = (u16*)&o2;
#pragma unroll
                for (int e = 0; e < 4; ++e) {
                    float th = pg * inv[e];
                    float sv = __sinf(th), cv = __cosf(th);  // v_sin/v_cos, |th|<=1023
                    float x1 = bf2f(cp[e]), x2 = bf2f(pp[e]);
                    o1p[e] = f2bf(x1 * cv - x2 * sv);
                    o2p[e] = f2bf(x2 * cv + x1 * sv);
                }
                const long rowb = (hb + p0 + pos_l) * 128;
                *(ushort4*)(dst + rowb + i0) = o1;
                *(ushort4*)(dst + rowb + i0 + 64) = o2;
            }
        } else {
            // V: store transposed into vT[32][128][1024]
            const long vrow = ((long)(b * 16 + h)) * 128;
#pragma unroll
            for (int c = 0; c < 8; ++c) {
                const int lin2 = c * 2048 + tid * 8;
                const int dk = lin2 >> 7;
                const int ps = lin2 & 127;
                ushort4 o1, o2;
                u16* o1p = (u16*)&o1;
                u16* o2p = (u16*)&o2;
#pragma unroll
                for (int e = 0; e < 4; ++e) {
                    o1p[e] = sm.T[(ps + e) * 132 + dk];
                    o2p[e] = sm.T[(ps + 4 + e) * 132 + dk];
                }
                u16* dst = vtb + (vrow + dk) * 1024 + p0 + ps;
                *(ushort4*)dst = o1;
                *(ushort4*)(dst + 4) = o2;
            }
        }
    } else {
        float bv[4];
#pragma unroll
        for (int j = 0; j < 4; ++j) bv[j] = bias[bn * 128 + wn * 64 + j * 16 + lm];
#pragma unroll
        for (int i = 0; i < MI; ++i) {
#pragma unroll
            for (int r = 0; r < 4; ++r) {
                const int row = bm * TM + wm * (TM / 2) + i * 16 + quad * 4 + r;
#pragma unroll
                for (int j = 0; j < 4; ++j) {
                    const int col = bn * 128 + wn * 64 + j * 16 + lm;
                    out[(long)row * 2048 + col] = acc[i][j][r] + bv[j];
                }
            }
        }
    }
}

// ---------------- flash attention (causal), S^T = K*Q^T, 2-phase dbuf prefetch ---------
// T1 XCD swizzle: 8 same-bh blocks land on one XCD -> K/V fetched once per L2, not 8x.
// T5 setprio around MFMA clusters (attn-verified +4-7%, m191).
// T13 defer-max: skip alpha rescale when __all(cmax - m_i <= 8) (P <= 2^8 safe in bf16).
__global__ __launch_bounds__(256, 2) void k_flash(const u16* __restrict__ Q,
                                                  const u16* __restrict__ Kb,
                                                  const u16* __restrict__ VT,
                                                  u16* __restrict__ R) {
    __shared__ u16 Ks[2][64 * 128];  // [key 64][d 128], swizzled mask 15
    __shared__ u16 Vs[2][128 * 64];  // [d 128][key 64], swizzled mask 7
    __shared__ u16 Ps[64 * 72];      // [q 64][key 64 + 8 pad]
    const int tid = threadIdx.x;
    const int lane = tid & 63, wave = tid >> 6;
    const int lm = lane & 15, quad = lane >> 4;
    const int id = (blockIdx.x & 7) * 64 + (blockIdx.x >> 3);  // T1 swizzle (512 blocks)
    const int g = id >> 8, rem = id & 255;
    const int bh = rem >> 3, s = rem & 7;
    const int qt = g ? (15 - s) : s;
    const long qkbase = (long)bh * 1024 * 128;
    const long vtbase = (long)bh * 128 * 1024;
    const int q0 = qt * 64;

    short8 qf[4];
    {
        const u16* qrow = Q + qkbase + (long)(q0 + wave * 16 + lm) * 128 + quad * 8;
#pragma unroll
        for (int kc = 0; kc < 4; ++kc) qf[kc] = *(const short8*)(qrow + kc * 32);
    }

    f32x4 o_acc[8] = {};
    float m_i = -INFINITY, l_i = 0.f;
    const float cl2e = 0.08838834764831845f * 1.4426950408889634f;  // 1/sqrt(128)*log2(e)

    const int kr = lane >> 4;
    const int vr = lane >> 3;
    const int vcb = (lane & 7) ^ vr;

    auto stage = [&](int buf, int kt) {
#pragma unroll
        for (int it = 0; it < 4; ++it) {
            int ch = wave * 4 + it;
            int krow = ch * 4 + kr;
            int kchunk = (lane & 15) ^ (krow & 15);
            gload_lds16(Kb + qkbase + (long)(kt * 64 + krow) * 128 + kchunk * 8,
                        (char*)Ks[buf] + ch * 1024);
            int vrow = ch * 8 + vr;
            gload_lds16(VT + vtbase + (long)vrow * 1024 + kt * 64 + vcb * 8,
                        (char*)Vs[buf] + ch * 1024);
        }
    };

    stage(0, 0);
    __syncthreads();  // implicit vmcnt(0): tile 0 ready
    int cur = 0;

    for (int kt = 0; kt <= qt; ++kt) {
        if (kt < qt) stage(cur ^ 1, kt + 1);  // issue prefetch, no wait
        asm volatile("" ::: "memory");        // keep issue before compute

        f32x4 s_acc[4] = {};
        __builtin_amdgcn_s_setprio(1);
#pragma unroll
        for (int kc = 0; kc < 4; ++kc) {
#pragma unroll
            for (int mi = 0; mi < 4; ++mi) {
                int row = mi * 16 + lm;
                int pc = (kc * 4 + quad) ^ lm;
                short8 ak = *(const short8*)&Ks[cur][row * 128 + pc * 8];
                s_acc[mi] = mfma_bf16(ak, qf[kc], s_acc[mi]);
            }
        }
        __builtin_amdgcn_s_setprio(0);
        const int qg = q0 + wave * 16 + lm;
        float t[4][4];
        float cmax = -INFINITY;
#pragma unroll
        for (int mi = 0; mi < 4; ++mi)
#pragma unroll
            for (int r = 0; r < 4; ++r) {
                int kg = kt * 64 + mi * 16 + quad * 4 + r;
                float val = (kg <= qg) ? s_acc[mi][r] * cl2e : -INFINITY;
                t[mi][r] = val;
                cmax = fmaxf(cmax, val);
            }
        cmax = fmaxf(cmax, __shfl_xor(cmax, 16));
        cmax = fmaxf(cmax, __shfl_xor(cmax, 32));
        // T13 defer-max: keep old max when per-row growth <= 8 (P bounded by 2^8)
        float m_new = fmaxf(m_i, cmax);
        const bool defer = __all(cmax - m_i <= 8.f);
        if (defer) m_new = m_i;
        float csum = 0.f;
#pragma unroll
        for (int mi = 0; mi < 4; ++mi)
#pragma unroll
            for (int r = 0; r < 4; ++r) {
                float p = exp2f(t[mi][r] - m_new);
                t[mi][r] = p;
                csum += p;
            }
        csum += __shfl_xor(csum, 16);
        csum += __shfl_xor(csum, 32);
        if (!defer) {
            float alpha = exp2f(m_i - m_new);
            float aq[4];
#pragma unroll
            for (int r = 0; r < 4; ++r) aq[r] = __shfl(alpha, quad * 4 + r, 64);
#pragma unroll
            for (int nt = 0; nt < 8; ++nt)
#pragma unroll
                for (int r = 0; r < 4; ++r) o_acc[nt][r] *= aq[r];
            l_i = l_i * alpha + csum;
        } else {
            l_i += csum;
        }
        m_i = m_new;
#pragma unroll
        for (int mi = 0; mi < 4; ++mi) {
            ushort4 pk;
            pk.x = f2bf(t[mi][0]); pk.y = f2bf(t[mi][1]);
            pk.z = f2bf(t[mi][2]); pk.w = f2bf(t[mi][3]);
            *(ushort4*)&Ps[(wave * 16 + lm) * 72 + mi * 16 + quad * 4] = pk;
        }
        __builtin_amdgcn_s_setprio(1);
#pragma unroll
        for (int kc = 0; kc < 2; ++kc) {
            short8 ap = *(const short8*)&Ps[(wave * 16 + lm) * 72 + kc * 32 + quad * 8];
#pragma unroll
            for (int nt = 0; nt < 8; ++nt) {
                int row = nt * 16 + lm;
                int pc = (kc * 4 + quad) ^ (lm & 7);
                short8 bv = *(const short8*)&Vs[cur][row * 64 + pc * 8];
                o_acc[nt] = mfma_bf16(ap, bv, o_acc[nt]);
            }
        }
        __builtin_amdgcn_s_setprio(0);
        __syncthreads();  // implicit vmcnt(0): prefetch landed; Ps WAR fence
        cur ^= 1;
    }
    float lq[4];
#pragma unroll
    for (int r = 0; r < 4; ++r) lq[r] = __shfl(l_i, quad * 4 + r, 64);
    const int b = bh >> 4, h = bh & 15;
#pragma unroll
    for (int nt = 0; nt < 8; ++nt)
#pragma unroll
        for (int r = 0; r < 4; ++r) {
            const int pos = q0 + wave * 16 + quad * 4 + r;
            const int col = h * 128 + nt * 16 + lm;
            R[((long)b * 1024 + pos) * 2048 + col] = f2bf(o_acc[nt][r] / lq[r]);
        }
}

extern "C" void kernel_launch(void* const* d_in, const int* in_sizes, int n_in,
                              void* d_out, int out_size, void* d_ws, size_t ws_size,
                              hipStream_t stream) {
    const float* x    = (const float*)d_in[0];
    const float* Wqkv = (const float*)d_in[2];
    const float* Wout = (const float*)d_in[3];
    const float* bout = (const float*)d_in[4];
    float* out = (float*)d_out;

    char* ws = (char*)d_ws;
    u16* x_bf  = (u16*)(ws);                 // 8MB; dead after qkv GEMM
    u16* rbuf  = x_bf;                       // reuse: written by flash
    u16* WqkvT = (u16*)(ws + (8L << 20));    // 24MB
    u16* WoutT = (u16*)(ws + (32L << 20));   // 8MB
    u16* qbuf  = (u16*)(ws + (40L << 20));   // 8MB (roped)
    u16* kbuf  = (u16*)(ws + (48L << 20));   // 8MB (roped)
    u16* vtbuf = (u16*)(ws + (56L << 20));   // 8MB, vT[32][128][1024]

    k_prep<<<8192, 256, 0, stream>>>(x, Wqkv, Wout, x_bf, WqkvT, WoutT);
    k_gemm<0, 128><<<dim3(16, 48), 256, 0, stream>>>(x_bf, WqkvT, 2048, qbuf, kbuf, vtbuf,
                                                     nullptr, nullptr);
    k_flash<<<512, 256, 0, stream>>>(qbuf, kbuf, vtbuf, rbuf);
    k_gemm<1, 64><<<dim3(32, 16), 256, 0, stream>>>(rbuf, WoutT, 2048, nullptr, nullptr,
                                                    nullptr, out, bout);
}